// Round 5
// baseline (11054.898 us; speedup 1.0000x reference)
//
#include <hip/hip_runtime.h>
#include <hip/hip_cooperative_groups.h>
#include <cmath>

namespace cg = cooperative_groups;

#define B_  32
#define T_  250
#define E_  256
#define U_  1024
#define FU_ 4096   // 4*U
#define VK_ 1280   // virtual K = U + E  ( [rk0 ; k0] )

typedef __attribute__((ext_vector_type(8)))  __bf16 bf16x8;
typedef __attribute__((ext_vector_type(4)))  float  f32x4;

__device__ __forceinline__ float sigf(float x) { return 1.f / (1.f + __expf(-x)); }

// ---------------------------------------------------------------------------
// One-time: transpose + hi/lo-split weights (unchanged from round 4, proven).
// WT[j][k] = (k<1024 ? rk0[k][j] : k0[k-1024][j]) as bf16 hi + bf16 lo.
// ---------------------------------------------------------------------------
__global__ __launch_bounds__(256) void wsplit_kernel(
    const float* __restrict__ rk0, const float* __restrict__ k0,
    __bf16* __restrict__ wt_hi, __bf16* __restrict__ wt_lo)
{
    __shared__ float tile[32][65];
    const int tid = threadIdx.x;
    const int jt  = blockIdx.x & 63;
    const int kt  = blockIdx.x >> 6;
    const int gk0 = kt * 32;
    const int j0  = jt * 64;

    {
        const int c = tid & 63, r4 = tid >> 6;
        #pragma unroll
        for (int i = 0; i < 8; ++i) {
            const int r  = r4 * 8 + i;
            const int gk = gk0 + r;
            const float* src = (gk < U_) ? (rk0 + (size_t)gk * FU_ + j0 + c)
                                         : (k0 + (size_t)(gk - U_) * FU_ + j0 + c);
            tile[r][c] = *src;
        }
    }
    __syncthreads();
    {
        const int j_loc = tid >> 2, kseg = tid & 3;
        bf16x8 hi, lo;
        #pragma unroll
        for (int i = 0; i < 8; ++i) {
            const float  v  = tile[kseg * 8 + i][j_loc];
            const __bf16 hv = (__bf16)v;
            hi[i] = hv;
            lo[i] = (__bf16)(v - (float)hv);
        }
        const size_t off = (size_t)(j0 + j_loc) * VK_ + gk0 + kseg * 8;
        *(bf16x8*)(wt_hi + off) = hi;
        *(bf16x8*)(wt_lo + off) = lo;
    }
}

// ---------------------------------------------------------------------------
// Persistent cooperative LSTM recurrence: all 250 steps, one grid.sync/step.
// Grid 64 x 512. Block owns units [u0,u0+16). Wave w = (m-tile w>>2, gate w&3)
// computes one 16x16 z-tile over FULL K=1280 via mfma_f32_16x16x32_bf16 x3
// (Markidis hi/lo, 3 independent acc chains). No cross-block z exchange.
// A-frag: row=lane&15, k=(lane>>4)*8+j. B-frag: col=lane&15, same k (16B from
// k-major WT). C: col=lane&15, row=(lane>>4)*4+reg [m89/m91].
// c-state: one register per thread. h: double-buffered bf16 hi/lo in ws.
// ---------------------------------------------------------------------------
__global__ __launch_bounds__(512) void lstm_persistent(
    const __bf16* __restrict__ wt_hi, const __bf16* __restrict__ wt_lo,
    const int* __restrict__ tokens, const float* __restrict__ emb,
    __bf16* __restrict__ h0_hi, __bf16* __restrict__ h0_lo,
    __bf16* __restrict__ h1_hi, __bf16* __restrict__ h1_lo,
    const float* __restrict__ b0)
{
    cg::grid_group grid = cg::this_grid();
    __shared__ float z_lds[32 * 65];   // [b][g*16+u], stride 65: conflict-light

    const int tid  = threadIdx.x;
    const int lane = tid & 63;
    const int w    = tid >> 6;            // 8 waves
    const int mt   = w >> 2;              // m-tile: batches [mt*16, mt*16+16)
    const int g    = w & 3;               // gate
    const int u0   = blockIdx.x * 16;     // owned units

    // GEMM-role indices
    const int arow = mt * 16 + (lane & 15);        // batch row for A
    const int kg   = (lane >> 4) * 8;              // k sub-offset (0,8,16,24)
    const int colz = g * U_ + u0 + (lane & 15);    // z column in [0,4096)
    const __bf16* wph = wt_hi + (size_t)colz * VK_;
    const __bf16* wpl = wt_lo + (size_t)colz * VK_;

    // pointwise-role indices
    const int pb = tid >> 4;              // 0..31
    const int pu = tid & 15;              // 0..15
    const int ci = pb * U_ + u0 + pu;
    const float bi = b0[0 * U_ + u0 + pu];
    const float bf = b0[1 * U_ + u0 + pu];
    const float bg = b0[2 * U_ + u0 + pu];
    const float bo = b0[3 * U_ + u0 + pu];

    float c_reg = 0.f;

    // init h buf0 (this block's slice) to zero, then make visible grid-wide
    h0_hi[ci] = (__bf16)0.f;
    h0_lo[ci] = (__bf16)0.f;
    grid.sync();

    for (int t = 0; t < T_; ++t) {
        const __bf16* hh = (t & 1) ? h1_hi : h0_hi;
        const __bf16* hl = (t & 1) ? h1_lo : h0_lo;
        __bf16* nhh = (t & 1) ? h0_hi : h1_hi;
        __bf16* nhl = (t & 1) ? h0_lo : h1_lo;

        f32x4 acc_hh = {}, acc_lh = {}, acc_hl = {};

        // --- h region: k in [0,1024), 32 k-steps ---
        const __bf16* hph = hh + (size_t)arow * U_ + kg;
        const __bf16* hpl = hl + (size_t)arow * U_ + kg;
        #pragma unroll 4
        for (int ks = 0; ks < 32; ++ks) {
            const int kf = ks * 32 + kg;
            const bf16x8 ahi = *(const bf16x8*)(hph + ks * 32);
            const bf16x8 alo = *(const bf16x8*)(hpl + ks * 32);
            const bf16x8 whi = *(const bf16x8*)(wph + kf);
            const bf16x8 wlo = *(const bf16x8*)(wpl + kf);
            acc_hh = __builtin_amdgcn_mfma_f32_16x16x32_bf16(ahi, whi, acc_hh, 0, 0, 0);
            acc_lh = __builtin_amdgcn_mfma_f32_16x16x32_bf16(alo, whi, acc_lh, 0, 0, 0);
            acc_hl = __builtin_amdgcn_mfma_f32_16x16x32_bf16(ahi, wlo, acc_hl, 0, 0, 0);
        }

        // --- emb region: k in [1024,1280), 8 k-steps, split fp32 on the fly ---
        const int tok = tokens[arow * T_ + t];
        const float* ep = emb + (size_t)tok * E_ + kg;
        #pragma unroll 2
        for (int ks = 32; ks < 40; ++ks) {
            const int kf = ks * 32 + kg;
            bf16x8 ahi, alo;
            const float* e8 = ep + (ks - 32) * 32;
            #pragma unroll
            for (int j = 0; j < 8; ++j) {
                const float  v  = e8[j];
                const __bf16 hv = (__bf16)v;
                ahi[j] = hv;
                alo[j] = (__bf16)(v - (float)hv);
            }
            const bf16x8 whi = *(const bf16x8*)(wph + kf);
            const bf16x8 wlo = *(const bf16x8*)(wpl + kf);
            acc_hh = __builtin_amdgcn_mfma_f32_16x16x32_bf16(ahi, whi, acc_hh, 0, 0, 0);
            acc_lh = __builtin_amdgcn_mfma_f32_16x16x32_bf16(alo, whi, acc_lh, 0, 0, 0);
            acc_hl = __builtin_amdgcn_mfma_f32_16x16x32_bf16(ahi, wlo, acc_hl, 0, 0, 0);
        }

        // --- z exchange via LDS ---
        #pragma unroll
        for (int r = 0; r < 4; ++r) {
            const int zrow = mt * 16 + (lane >> 4) * 4 + r;
            z_lds[zrow * 65 + g * 16 + (lane & 15)] =
                acc_hh[r] + acc_lh[r] + acc_hl[r];
        }
        __syncthreads();

        // --- pointwise: gates, c/h update (c in register) ---
        const float zi = z_lds[pb * 65 +  0 + pu] + bi;
        const float zf = z_lds[pb * 65 + 16 + pu] + bf;
        const float zg = z_lds[pb * 65 + 32 + pu] + bg;
        const float zo = z_lds[pb * 65 + 48 + pu] + bo;
        const float ii = sigf(zi), ff = sigf(zf);
        const float gg = tanhf(zg), oo = sigf(zo);
        const float cv = ff * c_reg + ii * gg;
        c_reg = cv;
        const float hv = oo * tanhf(cv);
        const __bf16 hb = (__bf16)hv;
        nhh[ci] = hb;
        nhl[ci] = (__bf16)(hv - (float)hb);

        grid.sync();   // h(t+1) visible grid-wide; also fences z_lds reuse
    }
    // T_=250 even: final h lands in buf0 (t=249 odd writes h0_*).
}

// ---------------------------------------------------------------------------
// Cell-1 z (fp32, off critical path): Pc[b][col] = x_last @ k1 + b1.
// ---------------------------------------------------------------------------
__global__ __launch_bounds__(256) void cell1_gemm(
    const int* __restrict__ tokens, const float* __restrict__ emb,
    const float* __restrict__ k1, const float* __restrict__ b1,
    float* __restrict__ Pc)
{
    const int tid  = threadIdx.x;
    const int lane = tid & 63;
    const int warp = tid >> 6;
    const int j  = blockIdx.x;
    const int ct = j & 15, bg = j >> 4;
    const int b  = bg * 4 + warp;
    const int col = ct * 256 + lane * 4;
    const int tok = tokens[b * T_ + (T_ - 1)];
    const float* wp = k1 + col;
    const float* xp = emb + (size_t)tok * E_;
    float4 acc = *reinterpret_cast<const float4*>(b1 + col);
    #pragma unroll 4
    for (int k4 = 0; k4 < 64; ++k4) {
        const float4 x4 = *reinterpret_cast<const float4*>(xp + k4 * 4);
        const float4 w0 = *reinterpret_cast<const float4*>(wp + (size_t)(k4 * 4 + 0) * FU_);
        const float4 w1 = *reinterpret_cast<const float4*>(wp + (size_t)(k4 * 4 + 1) * FU_);
        const float4 w2 = *reinterpret_cast<const float4*>(wp + (size_t)(k4 * 4 + 2) * FU_);
        const float4 w3 = *reinterpret_cast<const float4*>(wp + (size_t)(k4 * 4 + 3) * FU_);
        acc.x = fmaf(x4.x, w0.x, acc.x); acc.y = fmaf(x4.x, w0.y, acc.y);
        acc.z = fmaf(x4.x, w0.z, acc.z); acc.w = fmaf(x4.x, w0.w, acc.w);
        acc.x = fmaf(x4.y, w1.x, acc.x); acc.y = fmaf(x4.y, w1.y, acc.y);
        acc.z = fmaf(x4.y, w1.z, acc.z); acc.w = fmaf(x4.y, w1.w, acc.w);
        acc.x = fmaf(x4.z, w2.x, acc.x); acc.y = fmaf(x4.z, w2.y, acc.y);
        acc.z = fmaf(x4.z, w2.z, acc.z); acc.w = fmaf(x4.z, w2.w, acc.w);
        acc.x = fmaf(x4.w, w3.x, acc.x); acc.y = fmaf(x4.w, w3.y, acc.y);
        acc.z = fmaf(x4.w, w3.z, acc.z); acc.w = fmaf(x4.w, w3.w, acc.w);
    }
    *reinterpret_cast<float4*>(Pc + (size_t)b * FU_ + col) = acc;
}

// ---------------------------------------------------------------------------
// Final: out[b] = sigmoid( h0.wout[0:U] + h1.wout[U:2U] + bout ).
// h0 reconstructed from bf16 hi+lo pair; h1 on the fly from Pc.
// ---------------------------------------------------------------------------
__global__ __launch_bounds__(256) void final_kernel(
    const __bf16* __restrict__ h0_hi, const __bf16* __restrict__ h0_lo,
    const float* __restrict__ Pc,
    const float* __restrict__ wout, const float* __restrict__ bout,
    float* __restrict__ out)
{
    const int b = blockIdx.x;
    const int tid = threadIdx.x;
    float s = 0.f;
    for (int u = tid; u < U_; u += 256) {
        const float h0v = (float)h0_hi[b * U_ + u] + (float)h0_lo[b * U_ + u];
        const float zi = Pc[(size_t)b * FU_ + u];
        const float zg = Pc[(size_t)b * FU_ + 2 * U_ + u];
        const float zo = Pc[(size_t)b * FU_ + 3 * U_ + u];
        const float c1 = sigf(zi) * tanhf(zg);
        const float h1 = sigf(zo) * tanhf(c1);
        s += h0v * wout[u] + h1 * wout[U_ + u];
    }
    #pragma unroll
    for (int off = 32; off > 0; off >>= 1) s += __shfl_down(s, off, 64);
    __shared__ float part[4];
    if ((tid & 63) == 0) part[tid >> 6] = s;
    __syncthreads();
    if (tid == 0) {
        const float tot = part[0] + part[1] + part[2] + part[3] + bout[0];
        out[b] = 1.f / (1.f + __expf(-tot));
    }
}

extern "C" void kernel_launch(void* const* d_in, const int* in_sizes, int n_in,
                              void* d_out, int out_size, void* d_ws, size_t ws_size,
                              hipStream_t stream) {
    const int*   tokens = (const int*)  d_in[0];
    const float* emb    = (const float*)d_in[1];
    const float* k0     = (const float*)d_in[2];
    const float* rk0    = (const float*)d_in[3];
    const float* b0     = (const float*)d_in[4];
    const float* k1     = (const float*)d_in[5];
    // d_in[6] = rk1 unused: cell 1 runs from zero state.
    const float* b1     = (const float*)d_in[7];
    const float* wout   = (const float*)d_in[8];
    const float* bout   = (const float*)d_in[9];
    float* out = (float*)d_out;

    const size_t BU  = (size_t)B_ * U_;        // 32768
    const size_t BFU = (size_t)B_ * FU_;       // 131072
    const size_t WSZ = (size_t)FU_ * VK_;      // 5242880

    float*  Pc    = (float*)d_ws;              // cell-1 z  [32][4096] f32
    __bf16* h0_hi = (__bf16*)(Pc + BFU);
    __bf16* h0_lo = h0_hi + BU;
    __bf16* h1_hi = h0_lo + BU;
    __bf16* h1_lo = h1_hi + BU;
    __bf16* wt_hi = h1_lo + BU;                // [4096][1280] bf16
    __bf16* wt_lo = wt_hi + WSZ;
    // ws use: 512KB + 256KB + 21MB ~= 21.8 MB. State (h bufs, c-in-regs)
    // fully initialized inside the kernels every call.

    wsplit_kernel<<<2560, 256, 0, stream>>>(rk0, k0, wt_hi, wt_lo);
    cell1_gemm<<<128, 256, 0, stream>>>(tokens, emb, k1, b1, Pc);

    {
        void* args[] = {
            (void*)&wt_hi, (void*)&wt_lo, (void*)&tokens, (void*)&emb,
            (void*)&h0_hi, (void*)&h0_lo, (void*)&h1_hi, (void*)&h1_lo,
            (void*)&b0
        };
        hipLaunchCooperativeKernel((void*)lstm_persistent,
                                   dim3(64), dim3(512), args, 0, stream);
    }

    final_kernel<<<B_, 256, 0, stream>>>(h0_hi, h0_lo, Pc, wout, bout, out);
}

// Round 6
// 9368.696 us; speedup vs baseline: 1.1800x; 1.1800x over previous
//
#include <hip/hip_runtime.h>
#include <cmath>

#define B_  32
#define T_  250
#define E_  256
#define U_  1024
#define FU_ 4096   // 4*U
#define VK_ 1280   // virtual K = U + E  ( [rk0 ; k0] )

typedef __attribute__((ext_vector_type(8)))  __bf16 bf16x8;
typedef __attribute__((ext_vector_type(4)))  float  f32x4;

__device__ __forceinline__ float sigf(float x) { return 1.f / (1.f + __expf(-x)); }

// ---------------------------------------------------------------------------
// One-time: transpose + hi/lo-split weights (proven rounds 4-5).
// WT[j][k] = (k<1024 ? rk0[k][j] : k0[k-1024][j]) as bf16 hi + bf16 lo.
// ---------------------------------------------------------------------------
__global__ __launch_bounds__(256) void wsplit_kernel(
    const float* __restrict__ rk0, const float* __restrict__ k0,
    __bf16* __restrict__ wt_hi, __bf16* __restrict__ wt_lo)
{
    __shared__ float tile[32][65];
    const int tid = threadIdx.x;
    const int jt  = blockIdx.x & 63;
    const int kt  = blockIdx.x >> 6;
    const int gk0 = kt * 32;
    const int j0  = jt * 64;

    {
        const int c = tid & 63, r4 = tid >> 6;
        #pragma unroll
        for (int i = 0; i < 8; ++i) {
            const int r  = r4 * 8 + i;
            const int gk = gk0 + r;
            const float* src = (gk < U_) ? (rk0 + (size_t)gk * FU_ + j0 + c)
                                         : (k0 + (size_t)(gk - U_) * FU_ + j0 + c);
            tile[r][c] = *src;
        }
    }
    __syncthreads();
    {
        const int j_loc = tid >> 2, kseg = tid & 3;
        bf16x8 hi, lo;
        #pragma unroll
        for (int i = 0; i < 8; ++i) {
            const float  v  = tile[kseg * 8 + i][j_loc];
            const __bf16 hv = (__bf16)v;
            hi[i] = hv;
            lo[i] = (__bf16)(v - (float)hv);
        }
        const size_t off = (size_t)(j0 + j_loc) * VK_ + gk0 + kseg * 8;
        *(bf16x8*)(wt_hi + off) = hi;
        *(bf16x8*)(wt_lo + off) = lo;
    }
}

// ---------------------------------------------------------------------------
// ONE fused LSTM step (launch 250x; stream order = grid barrier, ~2us vs
// cg::grid_sync's measured ~42us). Grid 64 x 512. Block owns units
// [u0,u0+16) x all 4 gates x all 32 batches over FULL K=1280 -> no partials,
// no cross-block traffic. Wave w = (m-tile w>>2, gate w&3): one 16x16 z-tile
// via mfma_f32_16x16x32_bf16 x3 (Markidis hi/lo).
// A-frag: row=lane&15, k=(lane>>4)*8+j. B-frag: col=lane&15, same k (16B
// loads from k-major WT). C: col=lane&15, row=(lane>>4)*4+reg [m89/m91].
// z exchange via LDS; pointwise updates c (global fp32) and h(t+1) bf16 hi/lo.
// ---------------------------------------------------------------------------
__global__ __launch_bounds__(512) void step_fused(
    const __bf16* __restrict__ wt_hi, const __bf16* __restrict__ wt_lo,
    const int* __restrict__ tokens, const float* __restrict__ emb,
    const float* __restrict__ b0,
    const __bf16* __restrict__ hh, const __bf16* __restrict__ hl,
    __bf16* __restrict__ nhh, __bf16* __restrict__ nhl,
    float* __restrict__ c_st, int t)
{
    __shared__ float z_lds[32 * 65];

    const int tid  = threadIdx.x;
    const int lane = tid & 63;
    const int w    = tid >> 6;            // 8 waves
    const int mt   = w >> 2;              // m-tile: batches [mt*16, mt*16+16)
    const int g    = w & 3;               // gate
    const int u0   = blockIdx.x * 16;     // owned units

    const int arow = mt * 16 + (lane & 15);        // A row = batch
    const int kg   = (lane >> 4) * 8;              // k sub-offset (0,8,16,24)
    const int colz = g * U_ + u0 + (lane & 15);    // z column
    const __bf16* wph = wt_hi + (size_t)colz * VK_;
    const __bf16* wpl = wt_lo + (size_t)colz * VK_;

    f32x4 acc_hh = {}, acc_lh = {}, acc_hl = {};

    // --- h region: k in [0,1024), 32 k-steps ---
    const __bf16* hph = hh + (size_t)arow * U_ + kg;
    const __bf16* hpl = hl + (size_t)arow * U_ + kg;
    #pragma unroll 8
    for (int ks = 0; ks < 32; ++ks) {
        const int kf = ks * 32 + kg;
        const bf16x8 ahi = *(const bf16x8*)(hph + ks * 32);
        const bf16x8 alo = *(const bf16x8*)(hpl + ks * 32);
        const bf16x8 whi = *(const bf16x8*)(wph + kf);
        const bf16x8 wlo = *(const bf16x8*)(wpl + kf);
        acc_hh = __builtin_amdgcn_mfma_f32_16x16x32_bf16(ahi, whi, acc_hh, 0, 0, 0);
        acc_lh = __builtin_amdgcn_mfma_f32_16x16x32_bf16(alo, whi, acc_lh, 0, 0, 0);
        acc_hl = __builtin_amdgcn_mfma_f32_16x16x32_bf16(ahi, wlo, acc_hl, 0, 0, 0);
    }

    // --- emb region: k in [1024,1280), 8 k-steps, split fp32 on the fly ---
    const int tok = tokens[arow * T_ + t];
    const float* ep = emb + (size_t)tok * E_ + kg;
    #pragma unroll 2
    for (int ks = 32; ks < 40; ++ks) {
        const int kf = ks * 32 + kg;
        bf16x8 ahi, alo;
        const float* e8 = ep + (ks - 32) * 32;
        #pragma unroll
        for (int j = 0; j < 8; ++j) {
            const float  v  = e8[j];
            const __bf16 hv = (__bf16)v;
            ahi[j] = hv;
            alo[j] = (__bf16)(v - (float)hv);
        }
        const bf16x8 whi = *(const bf16x8*)(wph + kf);
        const bf16x8 wlo = *(const bf16x8*)(wpl + kf);
        acc_hh = __builtin_amdgcn_mfma_f32_16x16x32_bf16(ahi, whi, acc_hh, 0, 0, 0);
        acc_lh = __builtin_amdgcn_mfma_f32_16x16x32_bf16(alo, whi, acc_lh, 0, 0, 0);
        acc_hl = __builtin_amdgcn_mfma_f32_16x16x32_bf16(ahi, wlo, acc_hl, 0, 0, 0);
    }

    // --- z exchange via LDS ---
    #pragma unroll
    for (int r = 0; r < 4; ++r) {
        const int zrow = mt * 16 + (lane >> 4) * 4 + r;
        z_lds[zrow * 65 + g * 16 + (lane & 15)] =
            acc_hh[r] + acc_lh[r] + acc_hl[r];
    }
    __syncthreads();

    // --- pointwise: gates, c/h update; 512 thr = 32 b x 16 u ---
    const int pb = tid >> 4;
    const int pu = tid & 15;
    const int ci = pb * U_ + u0 + pu;
    const float zi = z_lds[pb * 65 +  0 + pu] + b0[0 * U_ + u0 + pu];
    const float zf = z_lds[pb * 65 + 16 + pu] + b0[1 * U_ + u0 + pu];
    const float zg = z_lds[pb * 65 + 32 + pu] + b0[2 * U_ + u0 + pu];
    const float zo = z_lds[pb * 65 + 48 + pu] + b0[3 * U_ + u0 + pu];
    const float ii = sigf(zi), ff = sigf(zf);
    const float gg = tanhf(zg), oo = sigf(zo);
    const float cv = ff * c_st[ci] + ii * gg;
    c_st[ci] = cv;
    const float hv = oo * tanhf(cv);
    const __bf16 hb = (__bf16)hv;
    nhh[ci] = hb;
    nhl[ci] = (__bf16)(hv - (float)hb);
}

// ---------------------------------------------------------------------------
// Cell-1 z (fp32, off critical path): Pc[b][col] = x_last @ k1 + b1.
// ---------------------------------------------------------------------------
__global__ __launch_bounds__(256) void cell1_gemm(
    const int* __restrict__ tokens, const float* __restrict__ emb,
    const float* __restrict__ k1, const float* __restrict__ b1,
    float* __restrict__ Pc)
{
    const int tid  = threadIdx.x;
    const int lane = tid & 63;
    const int warp = tid >> 6;
    const int j  = blockIdx.x;
    const int ct = j & 15, bg = j >> 4;
    const int b  = bg * 4 + warp;
    const int col = ct * 256 + lane * 4;
    const int tok = tokens[b * T_ + (T_ - 1)];
    const float* wp = k1 + col;
    const float* xp = emb + (size_t)tok * E_;
    float4 acc = *reinterpret_cast<const float4*>(b1 + col);
    #pragma unroll 4
    for (int k4 = 0; k4 < 64; ++k4) {
        const float4 x4 = *reinterpret_cast<const float4*>(xp + k4 * 4);
        const float4 w0 = *reinterpret_cast<const float4*>(wp + (size_t)(k4 * 4 + 0) * FU_);
        const float4 w1 = *reinterpret_cast<const float4*>(wp + (size_t)(k4 * 4 + 1) * FU_);
        const float4 w2 = *reinterpret_cast<const float4*>(wp + (size_t)(k4 * 4 + 2) * FU_);
        const float4 w3 = *reinterpret_cast<const float4*>(wp + (size_t)(k4 * 4 + 3) * FU_);
        acc.x = fmaf(x4.x, w0.x, acc.x); acc.y = fmaf(x4.x, w0.y, acc.y);
        acc.z = fmaf(x4.x, w0.z, acc.z); acc.w = fmaf(x4.x, w0.w, acc.w);
        acc.x = fmaf(x4.y, w1.x, acc.x); acc.y = fmaf(x4.y, w1.y, acc.y);
        acc.z = fmaf(x4.y, w1.z, acc.z); acc.w = fmaf(x4.y, w1.w, acc.w);
        acc.x = fmaf(x4.z, w2.x, acc.x); acc.y = fmaf(x4.z, w2.y, acc.y);
        acc.z = fmaf(x4.z, w2.z, acc.z); acc.w = fmaf(x4.z, w2.w, acc.w);
        acc.x = fmaf(x4.w, w3.x, acc.x); acc.y = fmaf(x4.w, w3.y, acc.y);
        acc.z = fmaf(x4.w, w3.z, acc.z); acc.w = fmaf(x4.w, w3.w, acc.w);
    }
    *reinterpret_cast<float4*>(Pc + (size_t)b * FU_ + col) = acc;
}

// ---------------------------------------------------------------------------
// Final: out[b] = sigmoid( h0.wout[0:U] + h1.wout[U:2U] + bout ).
// h0 from bf16 hi+lo; h1 on the fly from Pc (c=0 -> f-gate irrelevant).
// ---------------------------------------------------------------------------
__global__ __launch_bounds__(256) void final_kernel(
    const __bf16* __restrict__ h0_hi, const __bf16* __restrict__ h0_lo,
    const float* __restrict__ Pc,
    const float* __restrict__ wout, const float* __restrict__ bout,
    float* __restrict__ out)
{
    const int b = blockIdx.x;
    const int tid = threadIdx.x;
    float s = 0.f;
    for (int u = tid; u < U_; u += 256) {
        const float h0v = (float)h0_hi[b * U_ + u] + (float)h0_lo[b * U_ + u];
        const float zi = Pc[(size_t)b * FU_ + u];
        const float zg = Pc[(size_t)b * FU_ + 2 * U_ + u];
        const float zo = Pc[(size_t)b * FU_ + 3 * U_ + u];
        const float c1 = sigf(zi) * tanhf(zg);
        const float h1 = sigf(zo) * tanhf(c1);
        s += h0v * wout[u] + h1 * wout[U_ + u];
    }
    #pragma unroll
    for (int off = 32; off > 0; off >>= 1) s += __shfl_down(s, off, 64);
    __shared__ float part[4];
    if ((tid & 63) == 0) part[tid >> 6] = s;
    __syncthreads();
    if (tid == 0) {
        const float tot = part[0] + part[1] + part[2] + part[3] + bout[0];
        out[b] = 1.f / (1.f + __expf(-tot));
    }
}

extern "C" void kernel_launch(void* const* d_in, const int* in_sizes, int n_in,
                              void* d_out, int out_size, void* d_ws, size_t ws_size,
                              hipStream_t stream) {
    const int*   tokens = (const int*)  d_in[0];
    const float* emb    = (const float*)d_in[1];
    const float* k0     = (const float*)d_in[2];
    const float* rk0    = (const float*)d_in[3];
    const float* b0     = (const float*)d_in[4];
    const float* k1     = (const float*)d_in[5];
    // d_in[6] = rk1 unused: cell 1 runs from zero state.
    const float* b1     = (const float*)d_in[7];
    const float* wout   = (const float*)d_in[8];
    const float* bout   = (const float*)d_in[9];
    float* out = (float*)d_out;

    const size_t BU  = (size_t)B_ * U_;        // 32768
    const size_t BFU = (size_t)B_ * FU_;       // 131072
    const size_t WSZ = (size_t)FU_ * VK_;      // 5242880

    float*  Pc    = (float*)d_ws;              // [32][4096] f32     (512 KB)
    float*  c     = Pc + BFU;                  // [32][1024] f32     (128 KB)
    __bf16* h0_hi = (__bf16*)(c + BU);         // 64 KB each, contiguous with c
    __bf16* h0_lo = h0_hi + BU;
    __bf16* h1_hi = h0_lo + BU;
    __bf16* h1_lo = h1_hi + BU;
    __bf16* wt_hi = h1_lo + BU;                // [4096][1280] bf16 (10.5 MB)
    __bf16* wt_lo = wt_hi + WSZ;
    // ws use ~= 21.9 MB

    // zero c + h buf0 every call (one contiguous memset: c, h0_hi, h0_lo)
    hipMemsetAsync(c, 0, BU * sizeof(float) + 2 * BU * sizeof(__bf16), stream);

    wsplit_kernel<<<2560, 256, 0, stream>>>(rk0, k0, wt_hi, wt_lo);
    cell1_gemm<<<128, 256, 0, stream>>>(tokens, emb, k1, b1, Pc);

    for (int t = 0; t < T_; ++t) {
        const __bf16* hh = (t & 1) ? h1_hi : h0_hi;
        const __bf16* hl = (t & 1) ? h1_lo : h0_lo;
        __bf16* nhh = (t & 1) ? h0_hi : h1_hi;
        __bf16* nhl = (t & 1) ? h0_lo : h1_lo;
        step_fused<<<64, 512, 0, stream>>>(wt_hi, wt_lo, tokens, emb, b0,
                                           hh, hl, nhh, nhl, c, t);
    }
    // T_=250 even: final h lands in h0_* (t=249 reads h1, writes h0).

    final_kernel<<<B_, 256, 0, stream>>>(h0_hi, h0_lo, Pc, wout, bout, out);
}

// Round 7
// 1816.673 us; speedup vs baseline: 6.0852x; 5.1571x over previous
//
#include <hip/hip_runtime.h>
#include <cmath>

#define B_  32
#define T_  250
#define E_  256
#define U_  1024
#define FU_ 4096   // 4*U
#define VK_ 1280   // virtual K = U + E  ( [rk0 ; k0] )

typedef __attribute__((ext_vector_type(8)))  __bf16 bf16x8;
typedef __attribute__((ext_vector_type(4)))  float  f32x4;

__device__ __forceinline__ float sigf(float x) { return 1.f / (1.f + __expf(-x)); }

// ---------------------------------------------------------------------------
// One-time: transpose + hi/lo-split weights DIRECTLY into MFMA B-fragment
// order. Block bi (0..255) owns z-cols colset[c] = (c>>2)*U_ + bi*4 + (c&3),
// c = 0..15. For k-tile K (0..39), lane l (0..63) supplies
// W[K*32 + (l>>4)*8 + j][colset[l&15]], j=0..7 -> stored contiguously at
// wfrag[((bi*40 + K)*64 + l)*8 + j]. A wave's B-load is then ONE 1KB
// coalesced transaction (round-6 k-major layout was a 16-line gather).
// Same LDS-transpose tile as proven rounds 4-6; only dest addressing differs.
// ---------------------------------------------------------------------------
__global__ __launch_bounds__(256) void wsplit_kernel(
    const float* __restrict__ rk0, const float* __restrict__ k0,
    __bf16* __restrict__ wfh, __bf16* __restrict__ wfl)
{
    __shared__ float tile[32][65];
    const int tid = threadIdx.x;
    const int jt  = blockIdx.x & 63;   // 64-col tile (within one gate region)
    const int kt  = blockIdx.x >> 6;   // 32-k tile = fragment K index
    const int gk0 = kt * 32;
    const int j0  = jt * 64;

    {   // coalesced load 32 k-rows x 64 cols
        const int c = tid & 63, r4 = tid >> 6;
        #pragma unroll
        for (int i = 0; i < 8; ++i) {
            const int r  = r4 * 8 + i;
            const int gk = gk0 + r;
            const float* src = (gk < U_) ? (rk0 + (size_t)gk * FU_ + j0 + c)
                                         : (k0 + (size_t)(gk - U_) * FU_ + j0 + c);
            tile[r][c] = *src;
        }
    }
    __syncthreads();
    {   // fragment-order hi/lo store, 16B per store
        const int j_loc = tid >> 2, kseg = tid & 3;
        bf16x8 hi, lo;
        #pragma unroll
        for (int i = 0; i < 8; ++i) {
            const float  v  = tile[kseg * 8 + i][j_loc];
            const __bf16 hv = (__bf16)v;
            hi[i] = hv;
            lo[i] = (__bf16)(v - (float)hv);
        }
        const int col = j0 + j_loc;          // global z-col
        const int g   = col >> 10;
        const int u   = col & 1023;
        const int bi  = u >> 2;
        const int c   = g * 4 + (u & 3);
        const int l   = kseg * 16 + c;
        const size_t off = (((size_t)bi * 40 + kt) * 64 + l) * 8;
        *(bf16x8*)(wfh + off) = hi;
        *(bf16x8*)(wfl + off) = lo;
    }
}

// ---------------------------------------------------------------------------
// ONE fused LSTM step, launched 250x (stream order = grid barrier; measured:
// cg::grid_sync ~42us/step, kernel boundary ~2us). Grid 256 x 512.
// Block bi = units [bi*4, bi*4+4) x ALL 4 gates (16 z-cols) over full K=1280.
// Wave w = (mt = w&1 m-tile, kq = w>>1 K-quarter of 320): 10 k-tiles x 3 MFMA
// (Markidis hi/lo: Ah@Wh + Al@Wh + Ah@Wl). All loads 16B/lane, 1KB/wave,
// coalesced (fragment-order wfrag + hfrag). Block-local LDS reduce over kq,
// then 128 threads do gates + c/h update; h(t+1) written in A-frag order.
// h A-frag: row=lane&15, k=(lane>>4)*8+j; C: col=lane&15, row=(lane>>4)*4+r.
// ---------------------------------------------------------------------------
__global__ __launch_bounds__(512) void step_fused(
    const __bf16* __restrict__ wfh, const __bf16* __restrict__ wfl,
    const int* __restrict__ tokens, const float* __restrict__ emb,
    const float* __restrict__ b0,
    const __bf16* __restrict__ hfh, const __bf16* __restrict__ hfl,
    __bf16* __restrict__ nfh, __bf16* __restrict__ nfl,
    float* __restrict__ c_st, int t)
{
    __shared__ float part[4][32][18];   // [kq][row][c], stride 18: <=2-way banks

    const int tid  = threadIdx.x;
    const int lane = tid & 63;
    const int w    = tid >> 6;          // 8 waves
    const int mt   = w & 1;             // m-tile (batches mt*16..mt*16+15)
    const int kq   = w >> 1;            // K-quarter (320 k's)
    const int bi   = blockIdx.x;

    const int arow = mt * 16 + (lane & 15);     // batch row (emb path)
    const int tok  = tokens[arow * T_ + t];
    const float* ep = emb + (size_t)tok * E_;

    const __bf16* wbh = wfh + ((size_t)bi * 40) * 512 + lane * 8;
    const __bf16* wbl = wfl + ((size_t)bi * 40) * 512 + lane * 8;

    f32x4 acc_hh = {}, acc_lh = {}, acc_hl = {};

    #pragma unroll
    for (int s = 0; s < 10; ++s) {
        const int K = kq * 10 + s;      // k-tile 0..39
        const bf16x8 wh = *(const bf16x8*)(wbh + (size_t)K * 512);
        const bf16x8 wl = *(const bf16x8*)(wbl + (size_t)K * 512);
        bf16x8 ah, al;
        if (K < 32) {   // h region, fragment-order load: 1KB/wave coalesced
            const size_t ao = ((size_t)(K * 2 + mt) * 64 + lane) * 8;
            ah = *(const bf16x8*)(hfh + ao);
            al = *(const bf16x8*)(hfl + ao);
        } else {        // emb region: on-the-fly hi/lo split of fp32
            const float* e8 = ep + (K - 32) * 32 + (lane >> 4) * 8;
            #pragma unroll
            for (int j = 0; j < 8; ++j) {
                const float  v  = e8[j];
                const __bf16 hv = (__bf16)v;
                ah[j] = hv;
                al[j] = (__bf16)(v - (float)hv);
            }
        }
        acc_hh = __builtin_amdgcn_mfma_f32_16x16x32_bf16(ah, wh, acc_hh, 0, 0, 0);
        acc_lh = __builtin_amdgcn_mfma_f32_16x16x32_bf16(al, wh, acc_lh, 0, 0, 0);
        acc_hl = __builtin_amdgcn_mfma_f32_16x16x32_bf16(ah, wl, acc_hl, 0, 0, 0);
    }

    // --- kq-partial exchange ---
    #pragma unroll
    for (int r = 0; r < 4; ++r) {
        const int row = mt * 16 + (lane >> 4) * 4 + r;
        part[kq][row][lane & 15] = acc_hh[r] + acc_lh[r] + acc_hl[r];
    }
    __syncthreads();

    // --- reduce + gates + c/h update: 128 threads = 32 b x 4 u ---
    if (tid < 128) {
        const int b  = tid >> 2, uu = tid & 3;
        const int u0 = bi * 4;
        float z[4];
        #pragma unroll
        for (int g = 0; g < 4; ++g) {
            const int c = g * 4 + uu;
            float s2 = b0[g * U_ + u0 + uu];
            #pragma unroll
            for (int q = 0; q < 4; ++q) s2 += part[q][b][c];
            z[g] = s2;
        }
        const float ii = sigf(z[0]), ff = sigf(z[1]);
        const float gg = tanhf(z[2]), oo = sigf(z[3]);
        const int ci = b * U_ + u0 + uu;
        const float cv = ff * c_st[ci] + ii * gg;
        c_st[ci] = cv;
        const float hv = oo * tanhf(cv);
        const __bf16 hb = (__bf16)hv;
        const int u = u0 + uu;
        // next step's A-fragment address for element (row=b, k=u)
        const size_t fo = ((size_t)((u >> 5) * 2 + (b >> 4)) * 64
                           + ((u >> 3) & 3) * 16 + (b & 15)) * 8 + (u & 7);
        nfh[fo] = hb;
        nfl[fo] = (__bf16)(hv - (float)hb);
    }
}

// ---------------------------------------------------------------------------
// Cell-1 z (fp32, off critical path): Pc[b][col] = x_last @ k1 + b1.
// ---------------------------------------------------------------------------
__global__ __launch_bounds__(256) void cell1_gemm(
    const int* __restrict__ tokens, const float* __restrict__ emb,
    const float* __restrict__ k1, const float* __restrict__ b1,
    float* __restrict__ Pc)
{
    const int tid  = threadIdx.x;
    const int lane = tid & 63;
    const int warp = tid >> 6;
    const int j  = blockIdx.x;
    const int ct = j & 15, bg = j >> 4;
    const int b  = bg * 4 + warp;
    const int col = ct * 256 + lane * 4;
    const int tok = tokens[b * T_ + (T_ - 1)];
    const float* wp = k1 + col;
    const float* xp = emb + (size_t)tok * E_;
    float4 acc = *reinterpret_cast<const float4*>(b1 + col);
    #pragma unroll 4
    for (int k4 = 0; k4 < 64; ++k4) {
        const float4 x4 = *reinterpret_cast<const float4*>(xp + k4 * 4);
        const float4 w0 = *reinterpret_cast<const float4*>(wp + (size_t)(k4 * 4 + 0) * FU_);
        const float4 w1 = *reinterpret_cast<const float4*>(wp + (size_t)(k4 * 4 + 1) * FU_);
        const float4 w2 = *reinterpret_cast<const float4*>(wp + (size_t)(k4 * 4 + 2) * FU_);
        const float4 w3 = *reinterpret_cast<const float4*>(wp + (size_t)(k4 * 4 + 3) * FU_);
        acc.x = fmaf(x4.x, w0.x, acc.x); acc.y = fmaf(x4.x, w0.y, acc.y);
        acc.z = fmaf(x4.x, w0.z, acc.z); acc.w = fmaf(x4.x, w0.w, acc.w);
        acc.x = fmaf(x4.y, w1.x, acc.x); acc.y = fmaf(x4.y, w1.y, acc.y);
        acc.z = fmaf(x4.y, w1.z, acc.z); acc.w = fmaf(x4.y, w1.w, acc.w);
        acc.x = fmaf(x4.z, w2.x, acc.x); acc.y = fmaf(x4.z, w2.y, acc.y);
        acc.z = fmaf(x4.z, w2.z, acc.z); acc.w = fmaf(x4.z, w2.w, acc.w);
        acc.x = fmaf(x4.w, w3.x, acc.x); acc.y = fmaf(x4.w, w3.y, acc.y);
        acc.z = fmaf(x4.w, w3.z, acc.z); acc.w = fmaf(x4.w, w3.w, acc.w);
    }
    *reinterpret_cast<float4*>(Pc + (size_t)b * FU_ + col) = acc;
}

// ---------------------------------------------------------------------------
// Final: out[b] = sigmoid( h0.wout[0:U] + h1.wout[U:2U] + bout ).
// h0 read from A-fragment-layout bf16 hi+lo; h1 on the fly from Pc.
// ---------------------------------------------------------------------------
__global__ __launch_bounds__(256) void final_kernel(
    const __bf16* __restrict__ hfh, const __bf16* __restrict__ hfl,
    const float* __restrict__ Pc,
    const float* __restrict__ wout, const float* __restrict__ bout,
    float* __restrict__ out)
{
    const int b = blockIdx.x;
    const int tid = threadIdx.x;
    float s = 0.f;
    for (int u = tid; u < U_; u += 256) {
        const size_t fo = ((size_t)((u >> 5) * 2 + (b >> 4)) * 64
                           + ((u >> 3) & 3) * 16 + (b & 15)) * 8 + (u & 7);
        const float h0v = (float)hfh[fo] + (float)hfl[fo];
        const float zi = Pc[(size_t)b * FU_ + u];
        const float zg = Pc[(size_t)b * FU_ + 2 * U_ + u];
        const float zo = Pc[(size_t)b * FU_ + 3 * U_ + u];
        const float c1 = sigf(zi) * tanhf(zg);
        const float h1 = sigf(zo) * tanhf(c1);
        s += h0v * wout[u] + h1 * wout[U_ + u];
    }
    #pragma unroll
    for (int off = 32; off > 0; off >>= 1) s += __shfl_down(s, off, 64);
    __shared__ float partf[4];
    if ((tid & 63) == 0) partf[tid >> 6] = s;
    __syncthreads();
    if (tid == 0) {
        const float tot = partf[0] + partf[1] + partf[2] + partf[3] + bout[0];
        out[b] = 1.f / (1.f + __expf(-tot));
    }
}

extern "C" void kernel_launch(void* const* d_in, const int* in_sizes, int n_in,
                              void* d_out, int out_size, void* d_ws, size_t ws_size,
                              hipStream_t stream) {
    const int*   tokens = (const int*)  d_in[0];
    const float* emb    = (const float*)d_in[1];
    const float* k0     = (const float*)d_in[2];
    const float* rk0    = (const float*)d_in[3];
    const float* b0     = (const float*)d_in[4];
    const float* k1     = (const float*)d_in[5];
    // d_in[6] = rk1 unused: cell 1 runs from zero state.
    const float* b1     = (const float*)d_in[7];
    const float* wout   = (const float*)d_in[8];
    const float* bout   = (const float*)d_in[9];
    float* out = (float*)d_out;

    const size_t BU  = (size_t)B_ * U_;        // 32768
    const size_t BFU = (size_t)B_ * FU_;       // 131072
    const size_t WSZ = (size_t)FU_ * VK_;      // 5242880

    float*  Pc   = (float*)d_ws;               // [32][4096] f32   (512 KB)
    float*  c    = Pc + BFU;                   // [32][1024] f32   (128 KB)
    __bf16* hf0h = (__bf16*)(c + BU);          // h frag buf0 hi   (64 KB)
    __bf16* hf0l = hf0h + BU;                  // h frag buf0 lo
    __bf16* hf1h = hf0l + BU;                  // h frag buf1 hi
    __bf16* hf1l = hf1h + BU;                  // h frag buf1 lo
    __bf16* wfh  = hf1l + BU;                  // W frag hi (10.5 MB)
    __bf16* wfl  = wfh + WSZ;                  // W frag lo (10.5 MB)
    // ws use ~= 21.9 MB

    // zero c + h frag buf0 (contiguous: c, hf0h, hf0l) every call
    hipMemsetAsync(c, 0, BU * sizeof(float) + 2 * BU * sizeof(__bf16), stream);

    wsplit_kernel<<<2560, 256, 0, stream>>>(rk0, k0, wfh, wfl);
    cell1_gemm<<<128, 256, 0, stream>>>(tokens, emb, k1, b1, Pc);

    for (int t = 0; t < T_; ++t) {
        const __bf16* hh = (t & 1) ? hf1h : hf0h;
        const __bf16* hl = (t & 1) ? hf1l : hf0l;
        __bf16* nh = (t & 1) ? hf0h : hf1h;
        __bf16* nl = (t & 1) ? hf0l : hf1l;
        step_fused<<<256, 512, 0, stream>>>(wfh, wfl, tokens, emb, b0,
                                            hh, hl, nh, nl, c, t);
    }
    // T_=250 even: t=249 reads buf1, writes buf0 -> final h in buf0.

    final_kernel<<<B_, 256, 0, stream>>>(hf0h, hf0l, Pc, wout, bout, out);
}